// Round 10
// baseline (113.434 us; speedup 1.0000x reference)
//
#include <hip/hip_runtime.h>
#include <math.h>

#define VOCAB  30522
#define HIDDEN 768
#define EMB    128
#define BATCH  1024
#define QLEN   32
#define DLEN   180
#define NEGV   (-1e4f)

typedef __attribute__((ext_vector_type(8))) short bf16x8;
typedef __attribute__((ext_vector_type(4))) float f32x4;
typedef unsigned int u32;

__device__ __forceinline__ unsigned short f2bf(float x) {
  union { float f; unsigned u; } v; v.f = x;
  unsigned r = v.u + 0x7FFFu + ((v.u >> 16) & 1u);
  return (unsigned short)(r >> 16);
}
__device__ __forceinline__ float bf2f(unsigned short h) {
  union { float f; unsigned u; } v; v.u = ((unsigned)h) << 16;
  return v.f;
}
// split 2 fp32 -> packed bf16 hi pair + packed bf16 lo pair
__device__ __forceinline__ void split_pk(float x0, float x1, unsigned& h, unsigned& l) {
  asm("v_cvt_pk_bf16_f32 %0, %1, %2" : "=v"(h) : "v"(x0), "v"(x1));
  float h0, h1;
  h0 = __uint_as_float(h << 16);
  h1 = __uint_as_float(h & 0xffff0000u);
  float l0 = x0 - h0, l1 = x1 - h1;
  asm("v_cvt_pk_bf16_f32 %0, %1, %2" : "=v"(l) : "v"(l0), "v"(l1));
}
// async 16B global -> LDS (direct, no VGPR roundtrip)
__device__ __forceinline__ void gload16(const float* g, void* l) {
  __builtin_amdgcn_global_load_lds(
      (const __attribute__((address_space(1))) u32*)g,
      (__attribute__((address_space(3))) u32*)l, 16, 0, 0);
}

// ---------------------------------------------------------------------------
// Kernel 0: W [768][128] fp32 -> fragment-major bf16 hi/lo tables.
// ---------------------------------------------------------------------------
__global__ __launch_bounds__(256) void prep_wfrag(
    const float* __restrict__ W, unsigned short* __restrict__ wfh,
    unsigned short* __restrict__ wfl) {
  int g = blockIdx.x * 256 + threadIdx.x;   // 0..12287
  if (g >= 24 * 8 * 64) return;
  int lane = g & 63, nt = (g >> 6) & 7, kk = g >> 9;
  int lr = lane & 15, kq = lane >> 4;
  int n = nt * 16 + lr;
  int k0 = kk * 32 + kq * 8;
  unsigned short hh[8], ll[8];
#pragma unroll
  for (int j = 0; j < 8; ++j) {
    float x = W[(size_t)(k0 + j) * EMB + n];
    unsigned short hi = f2bf(x);
    hh[j] = hi;
    ll[j] = f2bf(x - bf2f(hi));
  }
  size_t base = (size_t)g * 8;
#pragma unroll
  for (int j = 0; j < 2; ++j) {
    *(ushort4*)(wfh + base + j * 4) = *(ushort4*)(hh + j * 4);
    *(ushort4*)(wfl + base + j * 4) = *(ushort4*)(ll + j * 4);
  }
}

// ---------------------------------------------------------------------------
// Kernel 1 (MEASUREMENT BUILD): identical R9 structure, but the whole proj
// pass runs 3x inside one dispatch (idempotent; same pebf written each rep).
// Purpose: (a) total-time arithmetic pins per-pass cost P; (b) the ~3P-long
// dispatch beats the harness fill ops into rocprof top-5, exposing proj's
// counters for the first time in a passing run.
// ---------------------------------------------------------------------------
__global__ __launch_bounds__(256) void colbert_proj_mfma(
    const float* __restrict__ emb, const unsigned short* __restrict__ wfh,
    const unsigned short* __restrict__ wfl, const float* __restrict__ bias,
    unsigned short* __restrict__ pebf) {
  __shared__ __align__(16) char smem[17408];  // dbuf 2x8KB; epilogue 16.9KB

  const int tid  = threadIdx.x;
  const int lane = tid & 63;
  const int wid  = tid >> 6;   // wave = n-strip (cols wid*32..+31)
  const int lr   = lane & 15;
  const int kq   = lane >> 4;
  const int row0 = blockIdx.x * 32;

#define GSRC(P, HC)                                                            \
  (emb + (size_t)(row0 + ((P) >> 4) > VOCAB - 1 ? VOCAB - 1                    \
                                                : row0 + ((P) >> 4)) * HIDDEN  \
       + (HC) * 64 + (((P) & 15) ^ (((P) >> 4) & 7)) * 4)

#define GLOAD(HC, BUF)                                                         \
  {                                                                            \
    char* d = smem + (BUF) * 8192;                                             \
    gload16(GSRC(tid, HC),       d + tid * 16);                                \
    gload16(GSRC(tid + 256, HC), d + 4096 + tid * 16);                         \
  }

#pragma unroll 1
  for (int rep = 0; rep < 3; ++rep) {
    f32x4 acc[2][2];
#pragma unroll
    for (int mi = 0; mi < 2; ++mi)
#pragma unroll
      for (int ni = 0; ni < 2; ++ni) acc[mi][ni] = (f32x4)0.f;

    __syncthreads();   // protect smem reuse across reps (epilogue readers)
    GLOAD(0, 0);
    __syncthreads();   // drain prologue loads

    for (int hc = 0; hc < 12; ++hc) {
      const int cur = hc & 1;
      if (hc < 11) GLOAD(hc + 1, cur ^ 1);   // async into other buffer
      // B fragments for this chunk (L2-resident): 16 VGPRs
      bf16x8 bh[2][2], bl[2][2];
#pragma unroll
      for (int kk = 0; kk < 2; ++kk)
#pragma unroll
        for (int ni = 0; ni < 2; ++ni) {
          size_t g = ((size_t)((hc * 2 + kk) * 8 + wid * 2 + ni) * 64 + lane) * 8;
          bh[kk][ni] = *(const bf16x8*)(wfh + g);
          bl[kk][ni] = *(const bf16x8*)(wfl + g);
        }
      char* Ab = smem + cur * 8192;
#pragma unroll
      for (int kk = 0; kk < 2; ++kk) {
        bf16x8 ah[2], al[2];
#pragma unroll
        for (int mi = 0; mi < 2; ++mi) {
          int row = mi * 16 + lr;
          int base = row * 256 + kk * 128 + kq * 32;
          float4 x0 = *(float4*)(Ab + ((base)      ^ ((row & 7) << 4)));
          float4 x1 = *(float4*)(Ab + ((base + 16) ^ ((row & 7) << 4)));
          union { unsigned u[4]; bf16x8 v; } H, L;
          split_pk(x0.x, x0.y, H.u[0], L.u[0]);
          split_pk(x0.z, x0.w, H.u[1], L.u[1]);
          split_pk(x1.x, x1.y, H.u[2], L.u[2]);
          split_pk(x1.z, x1.w, H.u[3], L.u[3]);
          ah[mi] = H.v; al[mi] = L.v;
        }
#pragma unroll
        for (int mi = 0; mi < 2; ++mi)
#pragma unroll
          for (int ni = 0; ni < 2; ++ni) {
            acc[mi][ni] = __builtin_amdgcn_mfma_f32_16x16x32_bf16(ah[mi], bh[kk][ni], acc[mi][ni], 0, 0, 0);
            acc[mi][ni] = __builtin_amdgcn_mfma_f32_16x16x32_bf16(ah[mi], bl[kk][ni], acc[mi][ni], 0, 0, 0);
            acc[mi][ni] = __builtin_amdgcn_mfma_f32_16x16x32_bf16(al[mi], bh[kk][ni], acc[mi][ni], 0, 0, 0);
          }
      }
      __syncthreads();   // one barrier per chunk
    }

    // epilogue: bias + L2-normalize -> bf16. Reuse LDS as fp32 ep[32][132].
    float* ep = (float*)smem;
#pragma unroll
    for (int ni = 0; ni < 2; ++ni) {
      int col = wid * 32 + ni * 16 + lr;
      float bb = bias[col];
#pragma unroll
      for (int mi = 0; mi < 2; ++mi)
#pragma unroll
        for (int j = 0; j < 4; ++j) {
          int r = mi * 16 + kq * 4 + j;   // C: col=lane&15, row=(lane>>4)*4+j
          ep[r * 132 + col] = acc[mi][ni][j] + bb;
        }
    }
    __syncthreads();
    {
      int row = tid >> 3, oct = tid & 7;   // 8 threads/row, 16 cols each
      float4 vv[4];
      float ss = 0.f;
#pragma unroll
      for (int i = 0; i < 4; ++i) {
        vv[i] = *(float4*)&ep[row * 132 + oct * 16 + i * 4];
        ss += vv[i].x * vv[i].x + vv[i].y * vv[i].y + vv[i].z * vv[i].z + vv[i].w * vv[i].w;
      }
      ss += __shfl_xor(ss, 1);
      ss += __shfl_xor(ss, 2);
      ss += __shfl_xor(ss, 4);
      float sc = 1.f / (sqrtf(ss) + 1e-12f);
      int gr = row0 + row;
      if (gr < VOCAB) {
        unsigned pk[8];
#pragma unroll
        for (int i = 0; i < 4; ++i) {
          pk[i * 2 + 0] = (unsigned)f2bf(vv[i].x * sc) | ((unsigned)f2bf(vv[i].y * sc) << 16);
          pk[i * 2 + 1] = (unsigned)f2bf(vv[i].z * sc) | ((unsigned)f2bf(vv[i].w * sc) << 16);
        }
        uint4* dst = (uint4*)(pebf + (size_t)gr * EMB + oct * 16);
        dst[0] = make_uint4(pk[0], pk[1], pk[2], pk[3]);
        dst[1] = make_uint4(pk[4], pk[5], pk[6], pk[7]);
      }
    }
  }
#undef GSRC
#undef GLOAD
}

// ---------------------------------------------------------------------------
// Kernel 2: per-batch MaxSim via MFMA (unchanged).
// ---------------------------------------------------------------------------
__global__ __launch_bounds__(256) void colbert_score_mfma(
    const int* __restrict__ qids, const int* __restrict__ qmask,
    const int* __restrict__ dids, const int* __restrict__ dmask,
    const unsigned short* __restrict__ pebf, float* __restrict__ out) {
  __shared__ int sqid[32];
  __shared__ int sdid[192];
  __shared__ unsigned char smsk[192];
  __shared__ float wmax[4][32];

  const int b    = blockIdx.x;
  const int tid  = threadIdx.x;
  const int lane = tid & 63;
  const int wid  = tid >> 6;
  const int lr   = lane & 15;
  const int kq   = lane >> 4;

  if (tid < 32) sqid[tid] = qids[b * QLEN + tid];
  if (tid < 192) {
    if (tid < DLEN) {
      sdid[tid] = dids[b * DLEN + tid];
      smsk[tid] = (unsigned char)(dmask[b * DLEN + tid] > 0 ? 1 : 0);
    } else {
      sdid[tid] = 0;
      smsk[tid] = 0;
    }
  }
  __syncthreads();

  bf16x8 af[2][4];
#pragma unroll
  for (int mi = 0; mi < 2; ++mi) {
    size_t base = (size_t)sqid[mi * 16 + lr] * EMB + kq * 8;
#pragma unroll
    for (int ks = 0; ks < 4; ++ks)
      af[mi][ks] = *(const bf16x8*)(pebf + base + ks * 32);
  }
  const int n0 = wid * 48;
  bf16x8 bfr[3][4];
#pragma unroll
  for (int ni = 0; ni < 3; ++ni) {
    size_t base = (size_t)sdid[n0 + ni * 16 + lr] * EMB + kq * 8;
#pragma unroll
    for (int ks = 0; ks < 4; ++ks)
      bfr[ni][ks] = *(const bf16x8*)(pebf + base + ks * 32);
  }

  f32x4 acc[2][3];
#pragma unroll
  for (int mi = 0; mi < 2; ++mi)
#pragma unroll
    for (int ni = 0; ni < 3; ++ni) acc[mi][ni] = (f32x4)0.f;

#pragma unroll
  for (int ks = 0; ks < 4; ++ks)
#pragma unroll
    for (int mi = 0; mi < 2; ++mi)
#pragma unroll
      for (int ni = 0; ni < 3; ++ni)
        acc[mi][ni] = __builtin_amdgcn_mfma_f32_16x16x32_bf16(af[mi][ks], bfr[ni][ks], acc[mi][ni], 0, 0, 0);

#pragma unroll
  for (int mi = 0; mi < 2; ++mi) {
#pragma unroll
    for (int j = 0; j < 4; ++j) {
      float m = -3.0e38f;
#pragma unroll
      for (int ni = 0; ni < 3; ++ni) {
        int t = n0 + ni * 16 + lr;
        float s = smsk[t] ? acc[mi][ni][j] : NEGV;
        m = fmaxf(m, s);
      }
#pragma unroll
      for (int x = 1; x < 16; x <<= 1) m = fmaxf(m, __shfl_xor(m, x));
      if (lr == 0) wmax[wid][mi * 16 + kq * 4 + j] = m;
    }
  }
  __syncthreads();

  if (tid < 32) {
    float m = fmaxf(fmaxf(wmax[0][tid], wmax[1][tid]),
                    fmaxf(wmax[2][tid], wmax[3][tid]));
    float s = m * (float)qmask[b * QLEN + tid];
#pragma unroll
    for (int x = 1; x < 32; x <<= 1) s += __shfl_xor(s, x);
    if (tid == 0) out[b] = s;
  }
}

// ---------------------------------------------------------------------------
extern "C" void kernel_launch(void* const* d_in, const int* in_sizes, int n_in,
                              void* d_out, int out_size, void* d_ws, size_t ws_size,
                              hipStream_t stream) {
  const int*   qids  = (const int*)d_in[0];
  const int*   qmask = (const int*)d_in[1];
  const int*   dids  = (const int*)d_in[2];
  const int*   dmask = (const int*)d_in[3];
  const float* emb   = (const float*)d_in[4];
  const float* W     = (const float*)d_in[5];
  const float* bias  = (const float*)d_in[6];
  float*       out   = (float*)d_out;

  char* ws = (char*)d_ws;
  unsigned short* pebf = (unsigned short*)ws;                 // 7,813,632 B
  unsigned short* wfh  = (unsigned short*)(ws + 7813632);     //   196,608 B
  unsigned short* wfl  = (unsigned short*)(ws + 7813632 + 196608);

  prep_wfrag<<<48, 256, 0, stream>>>(W, wfh, wfl);
  colbert_proj_mfma<<<(VOCAB + 31) / 32, 256, 0, stream>>>(emb, wfh, wfl, bias, pebf);
  colbert_score_mfma<<<BATCH, 256, 0, stream>>>(qids, qmask, dids, dmask, pebf, out);
}

// Round 11
// 63.413 us; speedup vs baseline: 1.7888x; 1.7888x over previous
//
#include <hip/hip_runtime.h>
#include <math.h>

#define VOCAB  30522
#define HIDDEN 768
#define EMB    128
#define BATCH  1024
#define QLEN   32
#define DLEN   180
#define NEGV   (-1e4f)

typedef __attribute__((ext_vector_type(8))) short bf16x8;
typedef __attribute__((ext_vector_type(4))) float f32x4;
typedef unsigned int u32;

__device__ __forceinline__ unsigned short f2bf(float x) {
  union { float f; unsigned u; } v; v.f = x;
  unsigned r = v.u + 0x7FFFu + ((v.u >> 16) & 1u);
  return (unsigned short)(r >> 16);
}
__device__ __forceinline__ float bf2f(unsigned short h) {
  union { float f; unsigned u; } v; v.u = ((unsigned)h) << 16;
  return v.f;
}
// split 2 fp32 -> packed bf16 hi pair + packed bf16 lo pair
__device__ __forceinline__ void split_pk(float x0, float x1, unsigned& h, unsigned& l) {
  asm("v_cvt_pk_bf16_f32 %0, %1, %2" : "=v"(h) : "v"(x0), "v"(x1));
  float h0, h1;
  h0 = __uint_as_float(h << 16);
  h1 = __uint_as_float(h & 0xffff0000u);
  float l0 = x0 - h0, l1 = x1 - h1;
  asm("v_cvt_pk_bf16_f32 %0, %1, %2" : "=v"(l) : "v"(l0), "v"(l1));
}
// async 16B global -> LDS (direct, no VGPR roundtrip)
__device__ __forceinline__ void gload16(const float* g, void* l) {
  __builtin_amdgcn_global_load_lds(
      (const __attribute__((address_space(1))) u32*)g,
      (__attribute__((address_space(3))) u32*)l, 16, 0, 0);
}

// ---------------------------------------------------------------------------
// Kernel 0: W [768][128] fp32 -> fragment-major bf16 hi/lo tables.
// wf[(c32*8 + nt)*64 + lane][j] holds W[c32*32 + (lane>>4)*8 + j][nt*16 + (lane&15)]
// ---------------------------------------------------------------------------
__global__ __launch_bounds__(256) void prep_wfrag(
    const float* __restrict__ W, unsigned short* __restrict__ wfh,
    unsigned short* __restrict__ wfl) {
  int g = blockIdx.x * 256 + threadIdx.x;   // 0..12287
  if (g >= 24 * 8 * 64) return;
  int lane = g & 63, nt = (g >> 6) & 7, kk = g >> 9;
  int lr = lane & 15, kq = lane >> 4;
  int n = nt * 16 + lr;
  int k0 = kk * 32 + kq * 8;
  unsigned short hh[8], ll[8];
#pragma unroll
  for (int j = 0; j < 8; ++j) {
    float x = W[(size_t)(k0 + j) * EMB + n];
    unsigned short hi = f2bf(x);
    hh[j] = hi;
    ll[j] = f2bf(x - bf2f(hi));
  }
  size_t base = (size_t)g * 8;
#pragma unroll
  for (int j = 0; j < 2; ++j) {
    *(ushort4*)(wfh + base + j * 4) = *(ushort4*)(hh + j * 4);
    *(ushort4*)(wfl + base + j * 4) = *(ushort4*)(ll + j * 4);
  }
}

// ---------------------------------------------------------------------------
// Kernel 1: pebf[v] = bf16(normalize(emb[v] @ W + b)), bf16x3-split MFMA.
// 1908 blocks x 16 rows x 256 thr (4 waves; wave = 32-col n-strip, all rows).
// WHOLE-K LDS RESIDENCY: block's full A-panel (16x768 fp32 = 48KB) staged in
// ONE prologue global_load_lds burst (linear dest, pre-swizzled source) ->
// ONE vmcnt drain per block; the 12-chunk MFMA loop is then barrier-free
// (A read-only in LDS, B-frags from L2-resident table). HBM latency paid
// once/block, overlapped across 3 blocks/CU. 3 barriers total per block.
// LDS layout: [hc=12][row=16][slot16=16], slot16 phys = logical ^ (row&7).
// ---------------------------------------------------------------------------
__global__ __launch_bounds__(256) void colbert_proj_mfma(
    const float* __restrict__ emb, const unsigned short* __restrict__ wfh,
    const unsigned short* __restrict__ wfl, const float* __restrict__ bias,
    unsigned short* __restrict__ pebf) {
  __shared__ __align__(16) char smem[49152];  // A-panel; epilogue reuses 8.5KB

  const int tid  = threadIdx.x;
  const int lane = tid & 63;
  const int wid  = tid >> 6;   // wave = n-strip (cols wid*32..+31)
  const int lr   = lane & 15;
  const int kq   = lane >> 4;
  const int row0 = blockIdx.x * 16;

  // ---- prologue: stage entire 16x768 A-panel, one drain ----
  {
    int srow = tid >> 4;                 // 0..15
    int gr = row0 + srow; if (gr > VOCAB - 1) gr = VOCAB - 1;
    const float* rowp = emb + (size_t)gr * HIDDEN
                        + (size_t)(((tid & 15) ^ (srow & 7)) * 4);
#pragma unroll
    for (int i = 0; i < 12; ++i) {
      // instr i covers chunk hc=i: dest slot = i*4096 + tid*16 (linear),
      // source col-float = i*64 + swizzled 16B-slot
      gload16(rowp + i * 64, smem + i * 4096 + tid * 16);
    }
  }
  __syncthreads();   // the block's ONLY HBM drain

  f32x4 acc[2];
  acc[0] = (f32x4)0.f; acc[1] = (f32x4)0.f;

  // ---- main loop: NO barriers ----
  for (int hc = 0; hc < 12; ++hc) {
    bf16x8 bh[2][2], bl[2][2];
#pragma unroll
    for (int kk = 0; kk < 2; ++kk)
#pragma unroll
      for (int ni = 0; ni < 2; ++ni) {
        size_t g = ((size_t)((hc * 2 + kk) * 8 + wid * 2 + ni) * 64 + lane) * 8;
        bh[kk][ni] = *(const bf16x8*)(wfh + g);
        bl[kk][ni] = *(const bf16x8*)(wfl + g);
      }
    char* Ab = smem + hc * 4096;
#pragma unroll
    for (int kk = 0; kk < 2; ++kk) {
      int s0 = kk * 8 + kq * 2;
      float4 x0 = *(float4*)(Ab + lr * 256 + ((s0)     ^ (lr & 7)) * 16);
      float4 x1 = *(float4*)(Ab + lr * 256 + ((s0 + 1) ^ (lr & 7)) * 16);
      union { unsigned u[4]; bf16x8 v; } H, L;
      split_pk(x0.x, x0.y, H.u[0], L.u[0]);
      split_pk(x0.z, x0.w, H.u[1], L.u[1]);
      split_pk(x1.x, x1.y, H.u[2], L.u[2]);
      split_pk(x1.z, x1.w, H.u[3], L.u[3]);
#pragma unroll
      for (int ni = 0; ni < 2; ++ni) {
        acc[ni] = __builtin_amdgcn_mfma_f32_16x16x32_bf16(H.v, bh[kk][ni], acc[ni], 0, 0, 0);
        acc[ni] = __builtin_amdgcn_mfma_f32_16x16x32_bf16(H.v, bl[kk][ni], acc[ni], 0, 0, 0);
        acc[ni] = __builtin_amdgcn_mfma_f32_16x16x32_bf16(L.v, bh[kk][ni], acc[ni], 0, 0, 0);
      }
    }
  }

  // ---- epilogue: bias + L2-normalize -> bf16. Reuse LDS as fp32 ep[16][132].
  __syncthreads();   // all A-reads done before overwrite
  float* ep = (float*)smem;
#pragma unroll
  for (int ni = 0; ni < 2; ++ni) {
    int col = wid * 32 + ni * 16 + lr;
    float bb = bias[col];
#pragma unroll
    for (int j = 0; j < 4; ++j) {
      int r = kq * 4 + j;              // C: col=lane&15, row=(lane>>4)*4+j
      ep[r * 132 + col] = acc[ni][j] + bb;
    }
  }
  __syncthreads();
  {
    int row = tid >> 4, g = tid & 15;  // 16 threads/row, 8 cols each
    float4 v0 = *(float4*)&ep[row * 132 + g * 8];
    float4 v1 = *(float4*)&ep[row * 132 + g * 8 + 4];
    float ss = v0.x * v0.x + v0.y * v0.y + v0.z * v0.z + v0.w * v0.w
             + v1.x * v1.x + v1.y * v1.y + v1.z * v1.z + v1.w * v1.w;
    ss += __shfl_xor(ss, 1);
    ss += __shfl_xor(ss, 2);
    ss += __shfl_xor(ss, 4);
    ss += __shfl_xor(ss, 8);
    float sc = 1.f / (sqrtf(ss) + 1e-12f);
    int gr = row0 + row;
    if (gr < VOCAB) {
      unsigned pk0 = (unsigned)f2bf(v0.x * sc) | ((unsigned)f2bf(v0.y * sc) << 16);
      unsigned pk1 = (unsigned)f2bf(v0.z * sc) | ((unsigned)f2bf(v0.w * sc) << 16);
      unsigned pk2 = (unsigned)f2bf(v1.x * sc) | ((unsigned)f2bf(v1.y * sc) << 16);
      unsigned pk3 = (unsigned)f2bf(v1.z * sc) | ((unsigned)f2bf(v1.w * sc) << 16);
      *(uint4*)(pebf + (size_t)gr * EMB + g * 8) = make_uint4(pk0, pk1, pk2, pk3);
    }
  }
}

// ---------------------------------------------------------------------------
// Kernel 2: per-batch MaxSim via MFMA, fragments gathered straight from the
// L2/L3-resident bf16 table (no data staging). One block = one batch.
// ---------------------------------------------------------------------------
__global__ __launch_bounds__(256) void colbert_score_mfma(
    const int* __restrict__ qids, const int* __restrict__ qmask,
    const int* __restrict__ dids, const int* __restrict__ dmask,
    const unsigned short* __restrict__ pebf, float* __restrict__ out) {
  __shared__ int sqid[32];
  __shared__ int sdid[192];
  __shared__ unsigned char smsk[192];
  __shared__ float wmax[4][32];

  const int b    = blockIdx.x;
  const int tid  = threadIdx.x;
  const int lane = tid & 63;
  const int wid  = tid >> 6;
  const int lr   = lane & 15;
  const int kq   = lane >> 4;

  if (tid < 32) sqid[tid] = qids[b * QLEN + tid];
  if (tid < 192) {
    if (tid < DLEN) {
      sdid[tid] = dids[b * DLEN + tid];
      smsk[tid] = (unsigned char)(dmask[b * DLEN + tid] > 0 ? 1 : 0);
    } else {
      sdid[tid] = 0;
      smsk[tid] = 0;
    }
  }
  __syncthreads();

  bf16x8 af[2][4];
#pragma unroll
  for (int mi = 0; mi < 2; ++mi) {
    size_t base = (size_t)sqid[mi * 16 + lr] * EMB + kq * 8;
#pragma unroll
    for (int ks = 0; ks < 4; ++ks)
      af[mi][ks] = *(const bf16x8*)(pebf + base + ks * 32);
  }
  const int n0 = wid * 48;
  bf16x8 bfr[3][4];
#pragma unroll
  for (int ni = 0; ni < 3; ++ni) {
    size_t base = (size_t)sdid[n0 + ni * 16 + lr] * EMB + kq * 8;
#pragma unroll
    for (int ks = 0; ks < 4; ++ks)
      bfr[ni][ks] = *(const bf16x8*)(pebf + base + ks * 32);
  }

  f32x4 acc[2][3];
#pragma unroll
  for (int mi = 0; mi < 2; ++mi)
#pragma unroll
    for (int ni = 0; ni < 3; ++ni) acc[mi][ni] = (f32x4)0.f;

#pragma unroll
  for (int ks = 0; ks < 4; ++ks)
#pragma unroll
    for (int mi = 0; mi < 2; ++mi)
#pragma unroll
      for (int ni = 0; ni < 3; ++ni)
        acc[mi][ni] = __builtin_amdgcn_mfma_f32_16x16x32_bf16(af[mi][ks], bfr[ni][ks], acc[mi][ni], 0, 0, 0);

#pragma unroll
  for (int mi = 0; mi < 2; ++mi) {
#pragma unroll
    for (int j = 0; j < 4; ++j) {
      float m = -3.0e38f;
#pragma unroll
      for (int ni = 0; ni < 3; ++ni) {
        int t = n0 + ni * 16 + lr;
        float s = smsk[t] ? acc[mi][ni][j] : NEGV;
        m = fmaxf(m, s);
      }
#pragma unroll
      for (int x = 1; x < 16; x <<= 1) m = fmaxf(m, __shfl_xor(m, x));
      if (lr == 0) wmax[wid][mi * 16 + kq * 4 + j] = m;
    }
  }
  __syncthreads();

  if (tid < 32) {
    float m = fmaxf(fmaxf(wmax[0][tid], wmax[1][tid]),
                    fmaxf(wmax[2][tid], wmax[3][tid]));
    float s = m * (float)qmask[b * QLEN + tid];
#pragma unroll
    for (int x = 1; x < 32; x <<= 1) s += __shfl_xor(s, x);
    if (tid == 0) out[b] = s;
  }
}

// ---------------------------------------------------------------------------
extern "C" void kernel_launch(void* const* d_in, const int* in_sizes, int n_in,
                              void* d_out, int out_size, void* d_ws, size_t ws_size,
                              hipStream_t stream) {
  const int*   qids  = (const int*)d_in[0];
  const int*   qmask = (const int*)d_in[1];
  const int*   dids  = (const int*)d_in[2];
  const int*   dmask = (const int*)d_in[3];
  const float* emb   = (const float*)d_in[4];
  const float* W     = (const float*)d_in[5];
  const float* bias  = (const float*)d_in[6];
  float*       out   = (float*)d_out;

  char* ws = (char*)d_ws;
  unsigned short* pebf = (unsigned short*)ws;                 // 7,813,632 B
  unsigned short* wfh  = (unsigned short*)(ws + 7813632);     //   196,608 B
  unsigned short* wfl  = (unsigned short*)(ws + 7813632 + 196608);

  prep_wfrag<<<48, 256, 0, stream>>>(W, wfh, wfl);
  colbert_proj_mfma<<<(VOCAB + 15) / 16, 256, 0, stream>>>(emb, wfh, wfl, bias, pebf);
  colbert_score_mfma<<<BATCH, 256, 0, stream>>>(qids, qmask, dids, dmask, pebf, out);
}